// Round 2
// baseline (166.658 us; speedup 1.0000x reference)
//
#include <hip/hip_runtime.h>
#include <hip/hip_bf16.h>

#define B_ 128
#define S_ 513
#define H_ 256

typedef __attribute__((ext_vector_type(8))) short short8;
typedef __attribute__((ext_vector_type(4))) float f32x4;

// fp32 -> bf16 round-to-nearest-even
static __device__ inline unsigned short f2bf(float f) {
    union { float f; unsigned int u; } v; v.f = f;
    unsigned int u = v.u;
    unsigned int r = u + 0x7fffu + ((u >> 16) & 1u);
    return (unsigned short)(r >> 16);
}

// One block = one s-position: M=128 (full batch), N=256 (full out dim),
// K=256 in BK=64 tiles. 512 threads = 8 waves in a 2(m) x 4(n) grid; each
// wave computes 64x64 via 4x4 tiles of mfma_f32_16x16x32_bf16.
// W[m] is staged once per block (vs twice in R1) -> W L2/L3 traffic halves.
__global__ __launch_bounds__(512, 4)
void sel_gemm_kernel(const float* __restrict__ x,
                     const float* __restrict__ W,
                     const float* __restrict__ bias,
                     float* __restrict__ out) {
    const int s = blockIdx.x;                       // 0..512
    const int m_idx = (s < 3) ? s : ((s & 1) ? 3 : 4);

    // +8 bf16 pad per row (144 B = 36 banks) -> near-conflict-free frag reads
    __shared__ unsigned short As[128 * 72];
    __shared__ unsigned short Bs[256 * 72];

    const int t    = threadIdx.x;
    const int lane = t & 63;
    const int w    = t >> 6;       // wave id 0..7
    const int wn   = w & 3;        // n-slice: wn*64
    const int wm   = w >> 2;       // m-slice: wm*64
    const int lrow = lane & 15;
    const int quad = lane >> 4;

    const float* xbase = x + (size_t)s * H_;                 // + b*(S_*H_)
    const float* Wbase = W + (size_t)m_idx * H_ * H_;

    f32x4 acc[4][4];
#pragma unroll
    for (int i = 0; i < 4; ++i)
#pragma unroll
        for (int j = 0; j < 4; ++j) {
            f32x4 z = {0.f, 0.f, 0.f, 0.f};
            acc[i][j] = z;
        }

    for (int kt = 0; kt < 4; ++kt) {
        const int k0 = kt * 64;
        __syncthreads();

        // Stage A: 128 rows(b) x 64 fp32 -> bf16 LDS. 2048 float4, 4/thread.
#pragma unroll
        for (int i = 0; i < 4; ++i) {
            int flat = i * 512 + t;
            int row  = flat >> 4;          // 0..127 (batch)
            int col  = (flat & 15) * 4;    // 0..60
            const float4 v = *(const float4*)(xbase + (size_t)row * (S_ * H_) + k0 + col);
            ushort4 p;
            p.x = f2bf(v.x); p.y = f2bf(v.y); p.z = f2bf(v.z); p.w = f2bf(v.w);
            *(ushort4*)&As[row * 72 + col] = p;
        }
        // Stage B: 256 rows(d) x 64 fp32 -> bf16 LDS. 4096 float4, 8/thread.
#pragma unroll 4
        for (int i = 0; i < 8; ++i) {
            int flat = i * 512 + t;
            int row  = flat >> 4;          // 0..255 (d)
            int col  = (flat & 15) * 4;
            const float4 v = *(const float4*)(Wbase + (size_t)row * H_ + k0 + col);
            ushort4 p;
            p.x = f2bf(v.x); p.y = f2bf(v.y); p.z = f2bf(v.z); p.w = f2bf(v.w);
            *(ushort4*)&Bs[row * 72 + col] = p;
        }
        __syncthreads();

        // Compute: 2 K-steps of 32 per BK=64 tile.
#pragma unroll
        for (int kk = 0; kk < 64; kk += 32) {
            const int kf = kk + quad * 8;
            short8 a_frag[4], b_frag[4];
#pragma unroll
            for (int i = 0; i < 4; ++i)
                a_frag[i] = *(const short8*)&As[(wm * 64 + i * 16 + lrow) * 72 + kf];
#pragma unroll
            for (int j = 0; j < 4; ++j)
                b_frag[j] = *(const short8*)&Bs[(wn * 64 + j * 16 + lrow) * 72 + kf];
#pragma unroll
            for (int i = 0; i < 4; ++i)
#pragma unroll
                for (int j = 0; j < 4; ++j)
                    acc[i][j] = __builtin_amdgcn_mfma_f32_16x16x32_bf16(
                        a_frag[i], b_frag[j], acc[i][j], 0, 0, 0);
        }
    }

    // Bias: sum of all 5 bias rows at each d this lane stores (L2-hit loads).
    float bsum[4];
#pragma unroll
    for (int j = 0; j < 4; ++j) {
        int d = wn * 64 + j * 16 + lrow;
        float sum = 0.f;
#pragma unroll
        for (int i = 0; i < 5; ++i) sum += bias[i * H_ + d];
        bsum[j] = sum;
    }

    // Epilogue. C/D layout (verified m89/m91): col = lane&15, row = quad*4+reg.
#pragma unroll
    for (int i = 0; i < 4; ++i) {
#pragma unroll
        for (int r = 0; r < 4; ++r) {
            int bg = wm * 64 + i * 16 + quad * 4 + r;   // global batch index
            float* orow = out + ((size_t)bg * S_ + s) * H_;
#pragma unroll
            for (int j = 0; j < 4; ++j) {
                int d = wn * 64 + j * 16 + lrow;
                orow[d] = acc[i][j][r] + bsum[j];
            }
        }
    }
}

extern "C" void kernel_launch(void* const* d_in, const int* in_sizes, int n_in,
                              void* d_out, int out_size, void* d_ws, size_t ws_size,
                              hipStream_t stream) {
    const float* x    = (const float*)d_in[0];
    const float* W    = (const float*)d_in[1];
    const float* bias = (const float*)d_in[2];
    float* out = (float*)d_out;

    dim3 grid(S_);       // one block per position; M=128 = full batch
    dim3 block(512);
    sel_gemm_kernel<<<grid, block, 0, stream>>>(x, W, bias, out);
}

// Round 3
// 154.479 us; speedup vs baseline: 1.0788x; 1.0788x over previous
//
#include <hip/hip_runtime.h>
#include <hip/hip_bf16.h>

#define B_ 128
#define S_ 513
#define H_ 256

typedef __attribute__((ext_vector_type(8))) short short8;
typedef __attribute__((ext_vector_type(4))) float f32x4;

// Pack 8 fp32 -> 8 bf16 (RNE) using the HW packed converter.
static __device__ inline short8 pack8(float4 a, float4 b) {
    union { short8 s; __hip_bfloat162 h[4]; } u;
    u.h[0] = __float22bfloat162_rn(make_float2(a.x, a.y));
    u.h[1] = __float22bfloat162_rn(make_float2(a.z, a.w));
    u.h[2] = __float22bfloat162_rn(make_float2(b.x, b.y));
    u.h[3] = __float22bfloat162_rn(make_float2(b.z, b.w));
    return u.s;
}

static __device__ inline unsigned short f2bf(float f) {
    union { float f; unsigned int u; } v; v.f = f;
    unsigned int u = v.u;
    unsigned int r = u + 0x7fffu + ((u >> 16) & 1u);
    return (unsigned short)(r >> 16);
}

// One block = one (s, batch-half). M=64, N=256, K=256 staged in ONE shot.
// Key change vs R1/R2: B (W[m]) is NOT staged through LDS -- within a block
// each W element is consumed by exactly one wave exactly once, so LDS
// staging of B was pure overhead and serialized the K loop behind barriers.
// Waves load B fragments directly from global (L2-resident W) and the
// compiler pipelines those loads under MFMA. A (x) IS shared by all 4 waves,
// so it is staged: full K=256 at once -> a single barrier for the whole
// kernel, 16 independent HBM loads/thread for deep MLP on the cold fetch.
__global__ __launch_bounds__(256, 3)
void sel_gemm_kernel(const float* __restrict__ x,
                     const float* __restrict__ W,
                     const float* __restrict__ bias,
                     float* __restrict__ out) {
    const int bx = blockIdx.x;
    const int s  = bx >> 1;        // 0..512
    const int h  = bx & 1;         // batch half
    const int m_idx = (s < 3) ? s : ((s & 1) ? 3 : 4);

    // 64 rows x 256 bf16, +8 pad (stride 264 shorts = 528 B) for frag reads
    __shared__ unsigned short As[64 * 264];

    const int t    = threadIdx.x;
    const int lane = t & 63;
    const int w    = t >> 6;       // wave id 0..3 = n-slice
    const int lrow = lane & 15;
    const int quad = lane >> 4;

    const float* xbase = x + ((size_t)(h * 64) * S_ + s) * H_;
    const float* Wbase = W + (size_t)m_idx * H_ * H_;

    // ---- Stage A: 64 rows x 256 fp32 -> bf16 LDS. 4096 float4, 16/thread.
    // Per i: each wave loads one full row (64 lanes x 16 B contiguous).
#pragma unroll
    for (int i = 0; i < 16; ++i) {
        int flat = i * 256 + t;
        int row  = flat >> 6;          // 0..63 (batch within half)
        int col  = (flat & 63) * 4;    // 0..252
        const float4 v = *(const float4*)(xbase + (size_t)row * (S_ * H_) + col);
        ushort4 p;
        p.x = f2bf(v.x); p.y = f2bf(v.y); p.z = f2bf(v.z); p.w = f2bf(v.w);
        *(ushort4*)&As[row * 264 + col] = p;
    }

    f32x4 acc[4][4];
#pragma unroll
    for (int i = 0; i < 4; ++i)
#pragma unroll
        for (int j = 0; j < 4; ++j) {
            f32x4 z = {0.f, 0.f, 0.f, 0.f};
            acc[i][j] = z;
        }

    // Per-lane W row pointers (d = w*64 + j*16 + lrow), uniform over kk.
    const float* Wrow[4];
#pragma unroll
    for (int j = 0; j < 4; ++j)
        Wrow[j] = Wbase + (size_t)(w * 64 + j * 16 + lrow) * H_;

    __syncthreads();   // the only barrier

    // ---- Main loop: 8 K-steps of 32. B fragments straight from global/L2.
#pragma unroll 2
    for (int kk = 0; kk < 8; ++kk) {
        const int kf = kk * 32 + quad * 8;
        short8 a_frag[4];
#pragma unroll
        for (int i = 0; i < 4; ++i)
            a_frag[i] = *(const short8*)&As[(i * 16 + lrow) * 264 + kf];
#pragma unroll
        for (int j = 0; j < 4; ++j) {
            const float4 w0 = *(const float4*)(Wrow[j] + kf);
            const float4 w1 = *(const float4*)(Wrow[j] + kf + 4);
            const short8 b_frag = pack8(w0, w1);
#pragma unroll
            for (int i = 0; i < 4; ++i)
                acc[i][j] = __builtin_amdgcn_mfma_f32_16x16x32_bf16(
                    a_frag[i], b_frag, acc[i][j], 0, 0, 0);
        }
    }

    // Bias: sum of all 5 bias rows at each d this lane stores (L2-hit loads).
    float bsum[4];
#pragma unroll
    for (int j = 0; j < 4; ++j) {
        int d = w * 64 + j * 16 + lrow;
        float sum = 0.f;
#pragma unroll
        for (int i = 0; i < 5; ++i) sum += bias[i * H_ + d];
        bsum[j] = sum;
    }

    // Epilogue. C/D layout (verified m89/m91): col = lane&15, row = quad*4+reg.
#pragma unroll
    for (int i = 0; i < 4; ++i) {
#pragma unroll
        for (int r = 0; r < 4; ++r) {
            int bg = h * 64 + i * 16 + quad * 4 + r;   // global batch index
            float* orow = out + ((size_t)bg * S_ + s) * H_;
#pragma unroll
            for (int j = 0; j < 4; ++j) {
                int d = w * 64 + j * 16 + lrow;
                orow[d] = acc[i][j][r] + bsum[j];
            }
        }
    }
}

extern "C" void kernel_launch(void* const* d_in, const int* in_sizes, int n_in,
                              void* d_out, int out_size, void* d_ws, size_t ws_size,
                              hipStream_t stream) {
    const float* x    = (const float*)d_in[0];
    const float* W    = (const float*)d_in[1];
    const float* bias = (const float*)d_in[2];
    float* out = (float*)d_out;

    dim3 grid(S_ * 2);   // (s, batch-half)
    dim3 block(256);
    sel_gemm_kernel<<<grid, block, 0, stream>>>(x, W, bias, out);
}

// Round 4
// 137.213 us; speedup vs baseline: 1.2146x; 1.1258x over previous
//
#include <hip/hip_runtime.h>
#include <hip/hip_bf16.h>

#define B_ 128
#define S_ 513
#define H_ 256
#define SH_ (S_ * H_)

typedef __attribute__((ext_vector_type(8))) short short8;
typedef __attribute__((ext_vector_type(4))) float f32x4;

// Pack 8 fp32 -> 8 bf16 (RNE) via the HW packed converter.
static __device__ inline short8 pack8(float4 a, float4 b) {
    union { short8 s; __hip_bfloat162 h[4]; } u;
    u.h[0] = __float22bfloat162_rn(make_float2(a.x, a.y));
    u.h[1] = __float22bfloat162_rn(make_float2(a.z, a.w));
    u.h[2] = __float22bfloat162_rn(make_float2(b.x, b.y));
    u.h[3] = __float22bfloat162_rn(make_float2(b.z, b.w));
    return u.s;
}

static __device__ inline unsigned short f2bf(float f) {
    union { float f; unsigned int u; } v; v.f = f;
    unsigned int u = v.u;
    unsigned int r = u + 0x7fffu + ((u >> 16) & 1u);
    return (unsigned short)(r >> 16);
}

// Prep: W fp32 -> bf16 (5*256*256 elems) + bias sum (256) into workspace.
__global__ void prep_kernel(const float* __restrict__ W,
                            const float* __restrict__ bias,
                            unsigned short* __restrict__ Wbf,
                            float* __restrict__ bsum) {
    int t = blockIdx.x * 256 + threadIdx.x;
    if (t < 5 * H_ * H_ / 4) {
        float4 v = *(const float4*)(W + (size_t)t * 4);
        ushort4 p;
        p.x = f2bf(v.x); p.y = f2bf(v.y); p.z = f2bf(v.z); p.w = f2bf(v.w);
        *(ushort4*)(Wbf + (size_t)t * 4) = p;
    }
    if (t < H_) {
        float s = 0.f;
#pragma unroll
        for (int i = 0; i < 5; ++i) s += bias[i * H_ + t];
        bsum[t] = s;
    }
}

// One block = one s-position. M=128 (full batch), N=256, K=256.
// 512 threads = 8 waves in 2(m) x 4(n); wave-tile 64x64 via 4x4 MFMA tiles.
//
// Structure: ALL global loads up front (B frags -> 128 regs/lane from L2;
// A tile -> 64 KB LDS in one shot, XOR-swizzled), ONE barrier, then a pure
// LDS+register MFMA loop with zero global accesses and zero barriers.
// MODE 0: W pre-converted to bf16 in ws. MODE 1: inline fp32 convert.
template <int MODE>
__global__ __launch_bounds__(512, 2)
void sel_gemm_kernel(const float* __restrict__ x,
                     const void* __restrict__ Wp,
                     const void* __restrict__ bp,
                     float* __restrict__ out) {
    const int s = blockIdx.x;                      // 0..512
    const int m_idx = (s < 3) ? s : ((s & 1) ? 3 : 4);

    // 128 rows x 256 bf16, unpadded (exactly 64 KB). 16-B chunks of row r are
    // stored at chunk index c ^ (r & 7) -> fragment reads are ~2-way (free).
    __shared__ unsigned short As[128 * 256];

    const int t    = threadIdx.x;
    const int lane = t & 63;
    const int w    = t >> 6;       // 0..7
    const int wn   = w & 3;        // n-slice: wn*64
    const int wm   = w >> 1 >> 1;  // m-slice: wm*64  (w>>2)
    const int lrow = lane & 15;
    const int quad = lane >> 4;

    // ---- B fragments: this wave's 64 W-rows x K=256 -> 32 short8 per lane.
    short8 bfr[4][8];
    if (MODE == 0) {
        const unsigned short* Wb =
            (const unsigned short*)Wp + (size_t)m_idx * H_ * H_;
#pragma unroll
        for (int j = 0; j < 4; ++j) {
            const unsigned short* wrow = Wb + (size_t)(wn * 64 + j * 16 + lrow) * H_;
#pragma unroll
            for (int kk = 0; kk < 8; ++kk)
                bfr[j][kk] = *(const short8*)(wrow + kk * 32 + quad * 8);
        }
    } else {
        const float* Wb = (const float*)Wp + (size_t)m_idx * H_ * H_;
#pragma unroll
        for (int j = 0; j < 4; ++j) {
            const float* wrow = Wb + (size_t)(wn * 64 + j * 16 + lrow) * H_;
#pragma unroll
            for (int kk = 0; kk < 8; ++kk) {
                float4 v0 = *(const float4*)(wrow + kk * 32 + quad * 8);
                float4 v1 = *(const float4*)(wrow + kk * 32 + quad * 8 + 4);
                bfr[j][kk] = pack8(v0, v1);
            }
        }
    }

    // ---- Stage A: 128 rows x 256 fp32 -> bf16 LDS, swizzled. 8 chunks/thr.
    const float* xs = x + (size_t)s * H_;
#pragma unroll
    for (int i = 0; i < 8; ++i) {
        int flat = i * 512 + t;
        int r = flat >> 5;              // 0..127 (batch)
        int c = flat & 31;              // 16-B chunk (8 bf16) within row
        const float* src = xs + (size_t)r * SH_ + c * 8;
        float4 v0 = *(const float4*)src;
        float4 v1 = *(const float4*)(src + 4);
        *(short8*)&As[r * 256 + ((c ^ (r & 7)) * 8)] = pack8(v0, v1);
    }

    f32x4 acc[4][4];
#pragma unroll
    for (int i = 0; i < 4; ++i)
#pragma unroll
        for (int j = 0; j < 4; ++j) {
            f32x4 z = {0.f, 0.f, 0.f, 0.f};
            acc[i][j] = z;
        }

    __syncthreads();   // the only barrier

    // ---- Pure LDS+register MFMA loop: 8 K-steps of 32.
#pragma unroll
    for (int kk = 0; kk < 8; ++kk) {
        const int cc = kk * 4 + quad;   // chunk column of this lane's frag
        short8 afr[4];
#pragma unroll
        for (int i = 0; i < 4; ++i) {
            int r = wm * 64 + i * 16 + lrow;
            afr[i] = *(const short8*)&As[r * 256 + ((cc ^ (r & 7)) * 8)];
        }
#pragma unroll
        for (int j = 0; j < 4; ++j)
#pragma unroll
            for (int i = 0; i < 4; ++i)
                acc[i][j] = __builtin_amdgcn_mfma_f32_16x16x32_bf16(
                    afr[i], bfr[j][kk], acc[i][j], 0, 0, 0);
    }

    // ---- Bias
    float bs[4];
    if (MODE == 0) {
        const float* bsum = (const float*)bp;
#pragma unroll
        for (int j = 0; j < 4; ++j) bs[j] = bsum[wn * 64 + j * 16 + lrow];
    } else {
        const float* bias = (const float*)bp;
#pragma unroll
        for (int j = 0; j < 4; ++j) {
            int d = wn * 64 + j * 16 + lrow;
            float sum = 0.f;
#pragma unroll
            for (int i = 0; i < 5; ++i) sum += bias[i * H_ + d];
            bs[j] = sum;
        }
    }

    // ---- Epilogue. C/D layout: col = lane&15, row = quad*4+reg (m89/m91).
#pragma unroll
    for (int i = 0; i < 4; ++i) {
#pragma unroll
        for (int r = 0; r < 4; ++r) {
            int bg = wm * 64 + i * 16 + quad * 4 + r;   // batch index
            float* orow = out + ((size_t)bg * S_ + s) * H_;
#pragma unroll
            for (int j = 0; j < 4; ++j) {
                int d = wn * 64 + j * 16 + lrow;
                orow[d] = acc[i][j][r] + bs[j];
            }
        }
    }
}

extern "C" void kernel_launch(void* const* d_in, const int* in_sizes, int n_in,
                              void* d_out, int out_size, void* d_ws, size_t ws_size,
                              hipStream_t stream) {
    const float* x    = (const float*)d_in[0];
    const float* W    = (const float*)d_in[1];
    const float* bias = (const float*)d_in[2];
    float* out = (float*)d_out;

    const size_t w_elems  = (size_t)5 * H_ * H_;
    const size_t ws_need  = w_elems * sizeof(unsigned short) + H_ * sizeof(float);

    if (ws_size >= ws_need) {
        unsigned short* Wbf = (unsigned short*)d_ws;
        float* bsum = (float*)((char*)d_ws + w_elems * sizeof(unsigned short));
        prep_kernel<<<dim3((w_elems / 4 + 255) / 256), dim3(256), 0, stream>>>(
            W, bias, Wbf, bsum);
        sel_gemm_kernel<0><<<dim3(S_), dim3(512), 0, stream>>>(
            x, (const void*)Wbf, (const void*)bsum, out);
    } else {
        sel_gemm_kernel<1><<<dim3(S_), dim3(512), 0, stream>>>(
            x, (const void*)W, (const void*)bias, out);
    }
}